// Round 8
// baseline (153.922 us; speedup 1.0000x reference)
//
#include <hip/hip_runtime.h>
#include <hip/hip_bf16.h>
#include <math.h>

#define NCAP 10
#define DCAP 16
#define DIN  128
#define NPOS 4096
#define NB   64

// ---------------------------------------------------------------------------
// ws layout:
//   partial : f32 [64][16][128]      @ 0 B        (caps_sum chunk partials)
//   wbuf    : f32 [64][10][128]      @ 524288 B   (w = W_n @ v per (b,n))
//   pws     : f32 [64][16][10][128]  @ 851968 B   (per-256-pos partial sums)
//   ub      : bf16 [64][4096][128]   @ 6094848 B  (rounded copy of u, 67 MB)
// big path needs 73,203,712 B; else fall back to f32 routing.
// Every ws element is written before read -> no memset, no atomics.
// ---------------------------------------------------------------------------

__device__ inline float bflo(unsigned v) { return __uint_as_float(v << 16); }
__device__ inline float bfhi(unsigned v) { return __uint_as_float(v & 0xFFFF0000u); }
__device__ inline unsigned short f2bf(float f) {           // round-to-nearest-even
    unsigned u = __float_as_uint(f);
    return (unsigned short)((u + 0x7FFFu + ((u >> 16) & 1u)) >> 16);
}

// Pass A: per-batch column sum of u (coalesced, two-level); optionally also
// writes the bf16 copy ub (same layout as u).
template <int WRITE_BF>
__global__ __launch_bounds__(256) void caps_sum_cvt(const float* __restrict__ u,
                                                    float* __restrict__ partial,
                                                    ushort4* __restrict__ ub4) {
    const int b = blockIdx.x;
    const int chunk = blockIdx.y;          // 16 chunks of 256 positions
    const int t = threadIdx.x;
    const int v4 = t & 31;
    const int prow = t >> 5;
    const float4* up = (const float4*)u;
    const size_t posbase = (size_t)b * NPOS + chunk * 256;

    float4 acc = make_float4(0.f, 0.f, 0.f, 0.f);
    #pragma unroll 8
    for (int j = 0; j < 32; ++j) {
        const size_t idx = (posbase + prow + j * 8) * 32 + v4;
        float4 x = up[idx];
        if (WRITE_BF) {
            ushort4 h;
            h.x = f2bf(x.x); h.y = f2bf(x.y); h.z = f2bf(x.z); h.w = f2bf(x.w);
            ub4[idx] = h;
        }
        acc.x += x.x; acc.y += x.y; acc.z += x.z; acc.w += x.w;
    }
    __shared__ float4 red[8][32];
    red[prow][v4] = acc;
    __syncthreads();
    if (t < 32) {
        float4 s = red[0][t];
        #pragma unroll
        for (int r = 1; r < 8; ++r) {
            s.x += red[r][t].x; s.y += red[r][t].y;
            s.z += red[r][t].z; s.w += red[r][t].w;
        }
        ((float4*)partial)[((size_t)b * 16 + chunk) * 32 + t] = s;
    }
}

// Small per-(b,n): reduce chunk partials -> s -> squash -> v -> w (or out).
template <int MODE>
__global__ __launch_bounds__(128) void caps_small(const float* __restrict__ src,
                                                  const float* __restrict__ W,
                                                  float* __restrict__ dst) {
    const int b = blockIdx.x / NCAP;
    const int n = blockIdx.x % NCAP;
    const int t = threadIdx.x;             // 128 threads == din index

    __shared__ float xv[DIN];
    __shared__ float vv[DCAP];

    float a = 0.f;
    if (MODE == 0) {
        #pragma unroll 4
        for (int c = 0; c < 16; ++c)
            a += src[(size_t)(b * 16 + c) * DIN + t];
    } else {
        #pragma unroll 4
        for (int c = 0; c < 16; ++c)
            a += src[((size_t)(b * 16 + c) * NCAP + n) * DIN + t];
    }
    xv[t] = a;
    __syncthreads();

    if (t < DCAP) {
        float sv = 0.f;
        for (int d = 0; d < DIN; ++d)
            sv = fmaf(xv[d], W[d * (NCAP * DCAP) + n * DCAP + t], sv);
        if (MODE == 0) sv *= 0.1f;         // softmax of zeros over 10 capsules
        float nq = sv * sv;
        #pragma unroll
        for (int mm = 8; mm >= 1; mm >>= 1) nq += __shfl_xor(nq, mm, 16);
        nq += 1e-7f;
        const float coeff = sqrtf(nq) / (1.0f + nq);
        const float v = coeff * sv;
        if (MODE == 2)
            dst[(size_t)(b * NCAP + n) * DCAP + t] = v;
        else
            vv[t] = v;
    }
    if (MODE != 2) {
        __syncthreads();
        float wd = 0.f;
        #pragma unroll
        for (int dd = 0; dd < DCAP; ++dd)
            wd = fmaf(W[t * (NCAP * DCAP) + n * DCAP + dd], vv[dd], wd);
        dst[(size_t)(b * NCAP + n) * DIN + t] = wd;
    }
}

// bf16 routing pass. Block = 256 thr (4 waves) owns 256 positions, processed
// as four 64-pos subtiles through one XOR-swizzled 16 KB LDS tile.
// chunk = 16 B = 8 bf16 dims; (row r, chunk c) stored at c^(r&7).
__global__ __launch_bounds__(256, 4) void caps_route_bf(const unsigned short* __restrict__ ub,
                                                        const float* __restrict__ wsrc,
                                                        float* __restrict__ pdst) {
    const int b = blockIdx.x;
    const int tile = blockIdx.y;           // 16 tiles of 256 positions
    const int t = threadIdx.x;
    const int lane = t & 63;
    const int wv = __builtin_amdgcn_readfirstlane(t >> 6);

    __shared__ __align__(16) char smem[16384 + 11264];   // 27.6 KB
    uint4* tl = (uint4*)smem;                            // [64 rows][16 chunks]
    float (*lgp)[64][11] = (float (*)[64][11])(smem + 16384);
    float* red = (float*)smem;                           // fold reuse (20 KB)

    const float4* wq4 = (const float4*)(wsrc + (size_t)b * (NCAP * DIN));

    float acc0[NCAP], acc1[NCAP];          // dims {2*lane, 2*lane+1}
    #pragma unroll
    for (int n = 0; n < NCAP; ++n) { acc0[n] = 0.f; acc1[n] = 0.f; }

    for (int s = 0; s < 4; ++s) {
        __syncthreads();                   // tile safe to overwrite
        // ---- stage 64 pos x 128 bf16 dims, swizzled (coalesced global) ----
        const uint4* src4 = (const uint4*)(ub +
            ((size_t)b * NPOS + tile * 256 + s * 64) * DIN);
        #pragma unroll
        for (int i = 0; i < 4; ++i) {
            const int q = t + i * 256;     // 1024 chunks
            const int r = q >> 4, c = q & 15;
            tl[r * 16 + (c ^ (r & 7))] = src4[q];
        }
        __syncthreads();

        // ---- p1: wave wv handles dims [wv*32, wv*32+32), lane = pos ----
        float lg[NCAP];
        #pragma unroll
        for (int n = 0; n < NCAP; ++n) lg[n] = 0.f;
        #pragma unroll
        for (int j = 0; j < 4; ++j) {
            const int cc = wv * 4 + j;
            const uint4 uu = tl[lane * 16 + (cc ^ (lane & 7))];
            const float u0 = bflo(uu.x), u1 = bfhi(uu.x);
            const float u2 = bflo(uu.y), u3 = bfhi(uu.y);
            const float u4 = bflo(uu.z), u5 = bfhi(uu.z);
            const float u6 = bflo(uu.w), u7 = bfhi(uu.w);
            #pragma unroll
            for (int n = 0; n < NCAP; ++n) {
                const float4 wa = wq4[n * 32 + cc * 2];      // uniform -> s_load
                const float4 wb = wq4[n * 32 + cc * 2 + 1];
                lg[n] = fmaf(u0, wa.x, fmaf(u1, wa.y, fmaf(u2, wa.z,
                        fmaf(u3, wa.w, fmaf(u4, wb.x, fmaf(u5, wb.y,
                        fmaf(u6, wb.z, fmaf(u7, wb.w, lg[n]))))))));
            }
        }
        #pragma unroll
        for (int n = 0; n < NCAP; ++n) lgp[wv][lane][n] = lg[n];
        __syncthreads();

        // ---- combine quarters + softmax (lane = pos; redundant per wave) --
        float c[NCAP];
        float m = -1e30f;
        #pragma unroll
        for (int n = 0; n < NCAP; ++n) {
            c[n] = lgp[0][lane][n] + lgp[1][lane][n] +
                   lgp[2][lane][n] + lgp[3][lane][n];
            m = fmaxf(m, c[n]);
        }
        float ssum = 0.f;
        #pragma unroll
        for (int n = 0; n < NCAP; ++n) { c[n] = __expf(c[n] - m); ssum += c[n]; }
        const float inv = 1.0f / ssum;
        #pragma unroll
        for (int n = 0; n < NCAP; ++n) c[n] *= inv;

        // ---- p2: wave wv accumulates positions [wv*16, wv*16+16) ----------
        const unsigned* tlu = (const unsigned*)tl;
        const int chunk = lane >> 2, wsel = lane & 3;
        #pragma unroll
        for (int i = 0; i < 16; ++i) {
            const int p = wv * 16 + i;
            const unsigned v = tlu[(p * 16 + (chunk ^ (p & 7))) * 4 + wsel];
            const float f0 = bflo(v), f1 = bfhi(v);
            #pragma unroll
            for (int n = 0; n < NCAP; ++n) {
                const float cp = __int_as_float(
                    __builtin_amdgcn_readlane(__float_as_int(c[n]), p));
                acc0[n] = fmaf(cp, f0, acc0[n]);
                acc1[n] = fmaf(cp, f1, acc1[n]);
            }
        }
    }

    // ---- fold 4 per-wave partials, one coalesced partial store ----
    __syncthreads();
    #pragma unroll
    for (int n = 0; n < NCAP; ++n)
        ((float2*)(red + (size_t)(wv * NCAP + n) * DIN))[lane] =
            make_float2(acc0[n], acc1[n]);
    __syncthreads();
    float* pb = pdst + (size_t)(b * 16 + tile) * (NCAP * DIN);
    for (int k = t; k < NCAP * DIN; k += 256)
        pb[k] = red[k] + red[1280 + k] + red[2560 + k] + red[3840 + k];
}

// f32 routing pass (fallback when ws_size can't hold ub) — R7 version.
__global__ __launch_bounds__(256, 3) void caps_route(const float* __restrict__ u,
                                                     const float* __restrict__ wsrc,
                                                     float* __restrict__ pdst) {
    const int b = blockIdx.x;
    const int tile = blockIdx.y;
    const int t = threadIdx.x;
    const int lane = t & 63;
    const int wv = __builtin_amdgcn_readfirstlane(t >> 6);

    __shared__ float4 tl4[64 * 32];
    __shared__ float lgp[4][64][11];
    float* tlf = (float*)tl4;

    const float4* wq4 = (const float4*)(wsrc + (size_t)b * (NCAP * DIN));

    float acc0[NCAP], acc1[NCAP];
    #pragma unroll
    for (int n = 0; n < NCAP; ++n) { acc0[n] = 0.f; acc1[n] = 0.f; }

    for (int s = 0; s < 4; ++s) {
        __syncthreads();
        const float4* src4 = (const float4*)u +
            ((size_t)b * NPOS + tile * 256 + s * 64) * 32;
        #pragma unroll
        for (int i = 0; i < 8; ++i) {
            const int q = t + i * 256;
            const int r = q >> 5, c = q & 31;
            tl4[r * 32 + (c ^ (r & 7))] = src4[q];
        }
        __syncthreads();

        float lg[NCAP];
        #pragma unroll
        for (int n = 0; n < NCAP; ++n) lg[n] = 0.f;
        #pragma unroll
        for (int j = 0; j < 8; ++j) {
            const float4 u4 = tl4[lane * 32 + wv * 8 + (j ^ (lane & 7))];
            #pragma unroll
            for (int n = 0; n < NCAP; ++n) {
                const float4 w4 = wq4[n * 32 + wv * 8 + j];
                lg[n] = fmaf(u4.x, w4.x, fmaf(u4.y, w4.y,
                        fmaf(u4.z, w4.z, fmaf(u4.w, w4.w, lg[n]))));
            }
        }
        #pragma unroll
        for (int n = 0; n < NCAP; ++n) lgp[wv][lane][n] = lg[n];
        __syncthreads();

        float c[NCAP];
        float m = -1e30f;
        #pragma unroll
        for (int n = 0; n < NCAP; ++n) {
            c[n] = lgp[0][lane][n] + lgp[1][lane][n] +
                   lgp[2][lane][n] + lgp[3][lane][n];
            m = fmaxf(m, c[n]);
        }
        float ssum = 0.f;
        #pragma unroll
        for (int n = 0; n < NCAP; ++n) { c[n] = __expf(c[n] - m); ssum += c[n]; }
        const float inv = 1.0f / ssum;
        #pragma unroll
        for (int n = 0; n < NCAP; ++n) c[n] *= inv;

        const int col0 = lane >> 2, word = lane & 3;
        #pragma unroll
        for (int i = 0; i < 16; ++i) {
            const int p = wv * 16 + i;
            const int ca = col0 ^ (p & 7);
            const float u0 = tlf[(p * 32 + ca) * 4 + word];
            const float u1 = tlf[(p * 32 + ca + 16) * 4 + word];
            #pragma unroll
            for (int n = 0; n < NCAP; ++n) {
                const float cp = __int_as_float(
                    __builtin_amdgcn_readlane(__float_as_int(c[n]), p));
                acc0[n] = fmaf(cp, u0, acc0[n]);
                acc1[n] = fmaf(cp, u1, acc1[n]);
            }
        }
    }

    __syncthreads();
    float* red = tlf;
    #pragma unroll
    for (int n = 0; n < NCAP; ++n) {
        red[(wv * NCAP + n) * DIN + lane]      = acc0[n];
        red[(wv * NCAP + n) * DIN + lane + 64] = acc1[n];
    }
    __syncthreads();
    float* pb = pdst + (size_t)(b * 16 + tile) * (NCAP * DIN);
    for (int k = t; k < NCAP * DIN; k += 256)
        pb[k] = red[k] + red[1280 + k] + red[2560 + k] + red[3840 + k];
}

extern "C" void kernel_launch(void* const* d_in, const int* in_sizes, int n_in,
                              void* d_out, int out_size, void* d_ws, size_t ws_size,
                              hipStream_t stream) {
    const float* u = (const float*)d_in[0];   // [64][4096][128]
    const float* W = (const float*)d_in[1];   // [128][160]
    float* out = (float*)d_out;               // [64][10][16]
    float* ws = (float*)d_ws;

    float* partial = ws;                      // 131072 floats
    float* wbuf    = ws + 131072;             // 81920 floats
    float* pws     = ws + 212992;             // 1310720 floats (5.25 MB)
    unsigned short* ub = (unsigned short*)((char*)d_ws + 6094848); // 67 MB bf16

    const bool big = ws_size >= 73203712ull;  // host-known -> deterministic

    if (big) {
        caps_sum_cvt<1><<<dim3(NB, 16), 256, 0, stream>>>(u, partial, (ushort4*)ub);
        caps_small<0><<<NB * NCAP, 128, 0, stream>>>(partial, W, wbuf);
        caps_route_bf<<<dim3(NB, 16), 256, 0, stream>>>(ub, wbuf, pws);
        caps_small<1><<<NB * NCAP, 128, 0, stream>>>(pws, W, wbuf);
        caps_route_bf<<<dim3(NB, 16), 256, 0, stream>>>(ub, wbuf, pws);
        caps_small<2><<<NB * NCAP, 128, 0, stream>>>(pws, W, out);
    } else {
        caps_sum_cvt<0><<<dim3(NB, 16), 256, 0, stream>>>(u, partial, nullptr);
        caps_small<0><<<NB * NCAP, 128, 0, stream>>>(partial, W, wbuf);
        caps_route<<<dim3(NB, 16), 256, 0, stream>>>(u, wbuf, pws);
        caps_small<1><<<NB * NCAP, 128, 0, stream>>>(pws, W, wbuf);
        caps_route<<<dim3(NB, 16), 256, 0, stream>>>(u, wbuf, pws);
        caps_small<2><<<NB * NCAP, 128, 0, stream>>>(pws, W, out);
    }
}

// Round 10
// 106.769 us; speedup vs baseline: 1.4416x; 1.4416x over previous
//
#include <hip/hip_runtime.h>
#include <hip/hip_bf16.h>
#include <math.h>

#define NCAP 10
#define DCAP 16
#define DIN  128
#define NPOS 4096
#define NB   64

typedef short short8 __attribute__((ext_vector_type(8)));
typedef float floatx4 __attribute__((ext_vector_type(4)));

__device__ inline float bflo(unsigned v) { return __uint_as_float(v << 16); }
__device__ inline float bfhi(unsigned v) { return __uint_as_float(v & 0xFFFF0000u); }
__device__ inline unsigned short f2bf(float f) {           // round-to-nearest-even
    unsigned u = __float_as_uint(f);
    return (unsigned short)((u + 0x7FFFu + ((u >> 16) & 1u)) >> 16);
}
__device__ inline float bf2f(unsigned short h) { return __uint_as_float(((unsigned)h) << 16); }

// ===========================================================================
// BIG PATH (ws >= 86,679,552 B)
//   partial : f32 [64][16][4][128] @ 0         (per-wave col-sums of u, 2 MB)
//   vbuf    : f32 [64][10][16]     @ 2097152   (v per (b,n))
//   pws     : f32 [64][16][160]    @ 2138112   (per-block partial c*u_hat sums)
//   uhat    : bf16 [64][4096][160] @ 2793472   (u @ W, 83.9 MB)
// ===========================================================================

// Pass A: u_hat = u @ W via bf16 MFMA (f32 accum), rounded to bf16; also
// emits f32 column-sum partials of u (full precision) for iter-1's v1.
// Block 256 thr / 4 waves handles 256 positions as 4 chunks of 64.
__global__ __launch_bounds__(256) void gemm_uhat(const float* __restrict__ u,
                                                 const float* __restrict__ W,
                                                 uint4* __restrict__ uhat4,
                                                 float* __restrict__ partial) {
    const int b = blockIdx.x;
    const int blk = blockIdx.y;            // 16 blocks per b, 256 pos each
    const int t = threadIdx.x;
    const int l = t & 63;
    const int wv = __builtin_amdgcn_readfirstlane(t >> 6);

    __shared__ __align__(16) char lds[62464];
    short* WT = (short*)lds;               // [160 n][16 chunks][8 bf16], swizzled
    char* uio = lds + 40960;               // union: in 16384 B / out 21504 B

    // ---- stage W transposed to bf16 (once per block) ----
    const float4* W4 = (const float4*)W;   // [128][160] f32 = 5120 float4
    for (int i = t; i < 5120; i += 256) {
        const float4 wq = W4[i];
        const float* wqf = (const float*)&wq;
        const int k = i / 40;
        const int n0 = (i % 40) * 4;
        #pragma unroll
        for (int jj = 0; jj < 4; ++jj) {
            const int n = n0 + jj;
            WT[n * 128 + (((k >> 3) ^ (n & 15)) << 3) + (k & 7)] = f2bf(wqf[jj]);
        }
    }

    floatx4 cs0 = {0.f, 0.f, 0.f, 0.f}, cs1 = {0.f, 0.f, 0.f, 0.f};
    const float4* u4 = (const float4*)u;

    for (int cc = 0; cc < 4; ++cc) {
        __syncthreads();                   // union safe to overwrite
        const int pos0 = blk * 256 + cc * 64;
        uint4* in4 = (uint4*)uio;          // [64 pos][16 chunks], chunk^=(pos&15)

        // ---- stage in: f32 -> bf16, swizzled; accumulate col-sums ----
        #pragma unroll
        for (int i2 = 0; i2 < 4; ++i2) {
            const int q = t + i2 * 256;    // 1024 chunks
            const int pos = q >> 4, ch = q & 15;
            const size_t g = ((size_t)b * NPOS + pos0 + pos) * 32 + ch * 2;
            const float4 x0 = u4[g];
            const float4 x1 = u4[g + 1];
            cs0.x += x0.x; cs0.y += x0.y; cs0.z += x0.z; cs0.w += x0.w;
            cs1.x += x1.x; cs1.y += x1.y; cs1.z += x1.z; cs1.w += x1.w;
            uint4 h;
            h.x = (unsigned)f2bf(x0.x) | ((unsigned)f2bf(x0.y) << 16);
            h.y = (unsigned)f2bf(x0.z) | ((unsigned)f2bf(x0.w) << 16);
            h.z = (unsigned)f2bf(x1.x) | ((unsigned)f2bf(x1.y) << 16);
            h.w = (unsigned)f2bf(x1.z) | ((unsigned)f2bf(x1.w) << 16);
            in4[pos * 16 + (ch ^ (pos & 15))] = h;
        }
        __syncthreads();

        // ---- MFMA: wave wv owns m-tile wv (16 pos) x 10 n-tiles ----
        const short8* in8 = (const short8*)uio;
        short8 af[4];
        #pragma unroll
        for (int kk = 0; kk < 4; ++kk)
            af[kk] = in8[(16 * wv + (l & 15)) * 16 + ((kk * 4 + (l >> 4)) ^ (l & 15))];

        floatx4 acc[10];
        const short8* wt8 = (const short8*)WT;
        #pragma unroll
        for (int n = 0; n < 10; ++n) {
            floatx4 a = {0.f, 0.f, 0.f, 0.f};
            #pragma unroll
            for (int kk = 0; kk < 4; ++kk) {
                const short8 bf = wt8[(n * 16 + (l & 15)) * 16 +
                                      ((kk * 4 + (l >> 4)) ^ (l & 15))];
                a = __builtin_amdgcn_mfma_f32_16x16x32_bf16(af[kk], bf, a, 0, 0, 0);
            }
            acc[n] = a;
        }
        __syncthreads();                   // all frag reads done -> reuse union

        // ---- write C tile to out-LDS ([64 pos][168 shorts], 336 B rows) ----
        short* out16 = (short*)uio;
        #pragma unroll
        for (int n = 0; n < 10; ++n) {
            #pragma unroll
            for (int reg = 0; reg < 4; ++reg) {
                const int posl = 16 * wv + (l >> 4) * 4 + reg;
                out16[posl * 168 + n * 16 + (l & 15)] = f2bf(acc[n][reg]);
            }
        }
        __syncthreads();

        // ---- stage out to global (coalesced uint4) ----
        const uint4* o4 = (const uint4*)uio;
        #pragma unroll
        for (int i3 = 0; i3 < 5; ++i3) {
            const int q = t + i3 * 256;    // 1280 chunks
            const int pos = q / 20, ch = q % 20;
            uhat4[((size_t)b * NPOS + pos0 + pos) * 20 + ch] = o4[pos * 21 + ch];
        }
    }

    // ---- fold col-sums within wave, write per-wave partial ----
    #pragma unroll
    for (int mm = 16; mm <= 32; mm <<= 1) {
        cs0.x += __shfl_xor(cs0.x, mm); cs0.y += __shfl_xor(cs0.y, mm);
        cs0.z += __shfl_xor(cs0.z, mm); cs0.w += __shfl_xor(cs0.w, mm);
        cs1.x += __shfl_xor(cs1.x, mm); cs1.y += __shfl_xor(cs1.y, mm);
        cs1.z += __shfl_xor(cs1.z, mm); cs1.w += __shfl_xor(cs1.w, mm);
    }
    if (l < 16) {
        float4* p4 = (float4*)(partial + ((size_t)((b * 16 + blk) * 4 + wv)) * 128 + l * 8);
        p4[0] = make_float4(cs0.x, cs0.y, cs0.z, cs0.w);
        p4[1] = make_float4(cs1.x, cs1.y, cs1.z, cs1.w);
    }
}

// v1 from col-sum partials: s1 = 0.1 * (sum_i u) @ W -> squash -> vbuf.
__global__ __launch_bounds__(128) void small0(const float* __restrict__ partial,
                                              const float* __restrict__ W,
                                              float* __restrict__ vbuf) {
    const int b = blockIdx.x / NCAP;
    const int n = blockIdx.x % NCAP;
    const int t = threadIdx.x;
    __shared__ float xv[DIN];
    float a = 0.f;
    #pragma unroll 8
    for (int c = 0; c < 64; ++c)
        a += partial[(size_t)(b * 64 + c) * DIN + t];
    xv[t] = a;
    __syncthreads();
    if (t < DCAP) {
        float sv = 0.f;
        for (int d = 0; d < DIN; ++d)
            sv = fmaf(xv[d], W[d * 160 + n * DCAP + t], sv);
        sv *= 0.1f;
        float nq = sv * sv;
        #pragma unroll
        for (int mm = 8; mm >= 1; mm >>= 1) nq += __shfl_xor(nq, mm, 16);
        nq += 1e-7f;
        vbuf[(size_t)(b * NCAP + n) * DCAP + t] = sv * sqrtf(nq) / (1.0f + nq);
    }
}

// Routing on u_hat: per position 10 16-dim dots with v, softmax, accumulate
// c[n]*u_hat into per-block 160-f32 partial. Block 256 thr = 4 subtiles of 64.
__global__ __launch_bounds__(256, 4) void route_uhat(const uint4* __restrict__ uhat4,
                                                     const float* __restrict__ vbuf,
                                                     float* __restrict__ pws) {
    const int b = blockIdx.x;
    const int blk = blockIdx.y;            // 16 per b, 256 pos each
    const int t = threadIdx.x;
    const int l = t & 63;
    const int wv = __builtin_amdgcn_readfirstlane(t >> 6);

    __shared__ __align__(16) char tl[64 * 336];  // [64 pos][168 shorts] padded
    __shared__ float lgp[4][64][10];
    __shared__ float cs[64][10];
    short* tls = (short*)tl;
    uint4* tl4 = (uint4*)tl;

    const float* vb = vbuf + (size_t)b * 160;    // uniform -> scalar loads
    float acc = 0.f;

    for (int s = 0; s < 4; ++s) {
        __syncthreads();                   // prev p2 reads done
        const size_t base4 = ((size_t)b * NPOS + blk * 256 + s * 64) * 20;
        #pragma unroll
        for (int i = 0; i < 5; ++i) {
            const int q = t + i * 256;     // 1280 chunks
            tl4[(q / 20) * 21 + (q % 20)] = uhat4[base4 + q];
        }
        __syncthreads();

        // ---- p1: lane = pos, wave = d-quarter ----
        float lg[10];
        #pragma unroll
        for (int n = 0; n < 10; ++n) {
            const uint2 uu = *(const uint2*)&tls[l * 168 + n * 16 + wv * 4];
            lg[n] = bflo(uu.x) * vb[n * 16 + wv * 4]
                  + bfhi(uu.x) * vb[n * 16 + wv * 4 + 1]
                  + bflo(uu.y) * vb[n * 16 + wv * 4 + 2]
                  + bfhi(uu.y) * vb[n * 16 + wv * 4 + 3];
            lgp[wv][l][n] = lg[n];
        }
        __syncthreads();

        // ---- fold + softmax (redundant per wave); wave 0 publishes c ----
        float c[10];
        float m = -1e30f;
        #pragma unroll
        for (int n = 0; n < 10; ++n) {
            c[n] = lgp[0][l][n] + lgp[1][l][n] + lgp[2][l][n] + lgp[3][l][n];
            m = fmaxf(m, c[n]);
        }
        float ssum = 0.f;
        #pragma unroll
        for (int n = 0; n < 10; ++n) { c[n] = __expf(c[n] - m); ssum += c[n]; }
        const float inv = 1.0f / ssum;
        if (wv == 0) {
            #pragma unroll
            for (int n = 0; n < 10; ++n) cs[l][n] = c[n] * inv;
        }
        __syncthreads();

        // ---- p2: thread t<160 owns (n,d), sums all 64 positions ----
        if (t < 160) {
            const int n = t >> 4;
            for (int p = 0; p < 64; ++p)
                acc = fmaf(cs[p][n], bf2f((unsigned short)tls[p * 168 + t]), acc);
        }
    }
    if (t < 160) pws[(size_t)(b * 16 + blk) * 160 + t] = acc;
}

// Fold 16 block-partials -> s -> squash -> v (dst = vbuf or out).
__global__ __launch_bounds__(256) void smallv(const float* __restrict__ pws,
                                              float* __restrict__ dst) {
    const int b = blockIdx.x;
    const int t = threadIdx.x;
    if (t >= 160) return;
    float a = 0.f;
    #pragma unroll
    for (int c = 0; c < 16; ++c)
        a += pws[(size_t)(b * 16 + c) * 160 + t];
    float nq = a * a;
    #pragma unroll
    for (int mm = 8; mm >= 1; mm >>= 1) nq += __shfl_xor(nq, mm, 16);
    nq += 1e-7f;
    dst[(size_t)b * 160 + t] = a * sqrtf(nq) / (1.0f + nq);
}

// ===========================================================================
// FALLBACK PATH (R7, verified): f32 routing against w = W @ v.
// ws: partial f32[64][16][128] @0 ; wbuf @131072 f ; pws32 @212992 f (5.25MB)
// ===========================================================================

__global__ __launch_bounds__(256) void caps_sum(const float* __restrict__ u,
                                                float* __restrict__ partial) {
    const int b = blockIdx.x;
    const int chunk = blockIdx.y;
    const int t = threadIdx.x;
    const int v4 = t & 31;
    const int prow = t >> 5;
    const float4* up = (const float4*)u;
    const size_t posbase = (size_t)b * NPOS + chunk * 256;
    float4 acc = make_float4(0.f, 0.f, 0.f, 0.f);
    #pragma unroll 8
    for (int j = 0; j < 32; ++j) {
        float4 x = up[(posbase + prow + j * 8) * 32 + v4];
        acc.x += x.x; acc.y += x.y; acc.z += x.z; acc.w += x.w;
    }
    __shared__ float4 red[8][32];
    red[prow][v4] = acc;
    __syncthreads();
    if (t < 32) {
        float4 s = red[0][t];
        #pragma unroll
        for (int r = 1; r < 8; ++r) {
            s.x += red[r][t].x; s.y += red[r][t].y;
            s.z += red[r][t].z; s.w += red[r][t].w;
        }
        ((float4*)partial)[((size_t)b * 16 + chunk) * 32 + t] = s;
    }
}

template <int MODE>
__global__ __launch_bounds__(128) void caps_small(const float* __restrict__ src,
                                                  const float* __restrict__ W,
                                                  float* __restrict__ dst) {
    const int b = blockIdx.x / NCAP;
    const int n = blockIdx.x % NCAP;
    const int t = threadIdx.x;
    __shared__ float xv[DIN];
    __shared__ float vv[DCAP];
    float a = 0.f;
    if (MODE == 0) {
        #pragma unroll 4
        for (int c = 0; c < 16; ++c) a += src[(size_t)(b * 16 + c) * DIN + t];
    } else {
        #pragma unroll 4
        for (int c = 0; c < 16; ++c) a += src[((size_t)(b * 16 + c) * NCAP + n) * DIN + t];
    }
    xv[t] = a;
    __syncthreads();
    if (t < DCAP) {
        float sv = 0.f;
        for (int d = 0; d < DIN; ++d) sv = fmaf(xv[d], W[d * 160 + n * DCAP + t], sv);
        if (MODE == 0) sv *= 0.1f;
        float nq = sv * sv;
        #pragma unroll
        for (int mm = 8; mm >= 1; mm >>= 1) nq += __shfl_xor(nq, mm, 16);
        nq += 1e-7f;
        const float v = sv * sqrtf(nq) / (1.0f + nq);
        if (MODE == 2) dst[(size_t)(b * NCAP + n) * DCAP + t] = v;
        else vv[t] = v;
    }
    if (MODE != 2) {
        __syncthreads();
        float wd = 0.f;
        #pragma unroll
        for (int dd = 0; dd < DCAP; ++dd)
            wd = fmaf(W[t * 160 + n * DCAP + dd], vv[dd], wd);
        dst[(size_t)(b * NCAP + n) * DIN + t] = wd;
    }
}

__global__ __launch_bounds__(256, 3) void caps_route(const float* __restrict__ u,
                                                     const float* __restrict__ wsrc,
                                                     float* __restrict__ pdst) {
    const int b = blockIdx.x;
    const int tile = blockIdx.y;
    const int t = threadIdx.x;
    const int lane = t & 63;
    const int wv = __builtin_amdgcn_readfirstlane(t >> 6);
    __shared__ float4 tl4[64 * 32];
    __shared__ float lgp[4][64][11];
    float* tlf = (float*)tl4;
    const float4* wq4 = (const float4*)(wsrc + (size_t)b * (NCAP * DIN));
    float acc0[NCAP], acc1[NCAP];
    #pragma unroll
    for (int n = 0; n < NCAP; ++n) { acc0[n] = 0.f; acc1[n] = 0.f; }
    for (int s = 0; s < 4; ++s) {
        __syncthreads();
        const float4* src4 = (const float4*)u + ((size_t)b * NPOS + tile * 256 + s * 64) * 32;
        #pragma unroll
        for (int i = 0; i < 8; ++i) {
            const int q = t + i * 256;
            const int r = q >> 5, c = q & 31;
            tl4[r * 32 + (c ^ (r & 7))] = src4[q];
        }
        __syncthreads();
        float lg[NCAP];
        #pragma unroll
        for (int n = 0; n < NCAP; ++n) lg[n] = 0.f;
        #pragma unroll
        for (int j = 0; j < 8; ++j) {
            const float4 u4 = tl4[lane * 32 + wv * 8 + (j ^ (lane & 7))];
            #pragma unroll
            for (int n = 0; n < NCAP; ++n) {
                const float4 w4 = wq4[n * 32 + wv * 8 + j];
                lg[n] = fmaf(u4.x, w4.x, fmaf(u4.y, w4.y,
                        fmaf(u4.z, w4.z, fmaf(u4.w, w4.w, lg[n]))));
            }
        }
        #pragma unroll
        for (int n = 0; n < NCAP; ++n) lgp[wv][lane][n] = lg[n];
        __syncthreads();
        float c[NCAP];
        float m = -1e30f;
        #pragma unroll
        for (int n = 0; n < NCAP; ++n) {
            c[n] = lgp[0][lane][n] + lgp[1][lane][n] + lgp[2][lane][n] + lgp[3][lane][n];
            m = fmaxf(m, c[n]);
        }
        float ssum = 0.f;
        #pragma unroll
        for (int n = 0; n < NCAP; ++n) { c[n] = __expf(c[n] - m); ssum += c[n]; }
        const float inv = 1.0f / ssum;
        #pragma unroll
        for (int n = 0; n < NCAP; ++n) c[n] *= inv;
        const int col0 = lane >> 2, word = lane & 3;
        #pragma unroll
        for (int i = 0; i < 16; ++i) {
            const int p = wv * 16 + i;
            const int ca = col0 ^ (p & 7);
            const float u0 = tlf[(p * 32 + ca) * 4 + word];
            const float u1 = tlf[(p * 32 + ca + 16) * 4 + word];
            #pragma unroll
            for (int n = 0; n < NCAP; ++n) {
                const float cp = __int_as_float(
                    __builtin_amdgcn_readlane(__float_as_int(c[n]), p));
                acc0[n] = fmaf(cp, u0, acc0[n]);
                acc1[n] = fmaf(cp, u1, acc1[n]);
            }
        }
    }
    __syncthreads();
    float* red = tlf;
    #pragma unroll
    for (int n = 0; n < NCAP; ++n) {
        red[(wv * NCAP + n) * DIN + lane]      = acc0[n];
        red[(wv * NCAP + n) * DIN + lane + 64] = acc1[n];
    }
    __syncthreads();
    float* pb = pdst + (size_t)(b * 16 + tile) * (NCAP * DIN);
    for (int k = t; k < NCAP * DIN; k += 256)
        pb[k] = red[k] + red[1280 + k] + red[2560 + k] + red[3840 + k];
}

extern "C" void kernel_launch(void* const* d_in, const int* in_sizes, int n_in,
                              void* d_out, int out_size, void* d_ws, size_t ws_size,
                              hipStream_t stream) {
    const float* u = (const float*)d_in[0];   // [64][4096][128]
    const float* W = (const float*)d_in[1];   // [128][160]
    float* out = (float*)d_out;               // [64][10][16]
    char* wsb = (char*)d_ws;

    if (ws_size >= 86679552ull) {
        float* partial = (float*)wsb;                       // 2 MB
        float* vbuf    = (float*)(wsb + 2097152);           // 40 KB
        float* pws     = (float*)(wsb + 2138112);           // 640 KB
        uint4* uhat    = (uint4*)(wsb + 2793472);           // 83.9 MB bf16

        gemm_uhat<<<dim3(NB, 16), 256, 0, stream>>>(u, W, uhat, partial);
        small0<<<NB * NCAP, 128, 0, stream>>>(partial, W, vbuf);       // v1
        route_uhat<<<dim3(NB, 16), 256, 0, stream>>>(uhat, vbuf, pws); // iter 2
        smallv<<<NB, 256, 0, stream>>>(pws, vbuf);                     // v2
        route_uhat<<<dim3(NB, 16), 256, 0, stream>>>(uhat, vbuf, pws); // iter 3
        smallv<<<NB, 256, 0, stream>>>(pws, out);                      // v3 -> out
    } else {
        float* partial = (float*)wsb;
        float* wbuf    = (float*)wsb + 131072;
        float* pws32   = (float*)wsb + 212992;
        caps_sum<<<dim3(NB, 16), 256, 0, stream>>>(u, partial);
        caps_small<0><<<NB * NCAP, 128, 0, stream>>>(partial, W, wbuf);
        caps_route<<<dim3(NB, 16), 256, 0, stream>>>(u, wbuf, pws32);
        caps_small<1><<<NB * NCAP, 128, 0, stream>>>(pws32, W, wbuf);
        caps_route<<<dim3(NB, 16), 256, 0, stream>>>(u, wbuf, pws32);
        caps_small<2><<<NB * NCAP, 128, 0, stream>>>(pws32, W, out);
    }
}